// Round 3
// baseline (949.967 us; speedup 1.0000x reference)
//
#include <hip/hip_runtime.h>
#include <math.h>

#define N_NODES 50000
#define N_EDGES 800000

// ---------------- degree / CSR build ----------------

__global__ void k_degrees(const int* __restrict__ ei, int* __restrict__ deg_out,
                          int* __restrict__ deg_in) {
    int e = blockIdx.x * 256 + threadIdx.x;
    if (e < N_EDGES) {
        atomicAdd(&deg_out[ei[e]], 1);
        atomicAdd(&deg_in[ei[N_EDGES + e]], 1);
    }
}

__global__ void k_invsqrt(const int* __restrict__ deg_out, const int* __restrict__ deg_in,
                          float* __restrict__ inv_out, float* __restrict__ inv_in) {
    int n = blockIdx.x * 256 + threadIdx.x;
    if (n < N_NODES) {
        int a = deg_out[n]; if (a < 1) a = 1;
        int b = deg_in[n];  if (b < 1) b = 1;
        inv_out[n] = 1.0f / sqrtf((float)a);
        inv_in[n]  = 1.0f / sqrtf((float)b);
    }
}

// exclusive scan, 256-element blocks (Hillis-Steele)
__global__ void k_scan1(const int* __restrict__ in, int* __restrict__ out,
                        int* __restrict__ bsum, int n) {
    __shared__ int s[256];
    int i = blockIdx.x * 256 + threadIdx.x;
    int v = (i < n) ? in[i] : 0;
    s[threadIdx.x] = v;
    __syncthreads();
    for (int off = 1; off < 256; off <<= 1) {
        int t = (threadIdx.x >= off) ? s[threadIdx.x - off] : 0;
        __syncthreads();
        s[threadIdx.x] += t;
        __syncthreads();
    }
    if (i < n) out[i] = s[threadIdx.x] - v;   // exclusive
    if (threadIdx.x == 255 && bsum) bsum[blockIdx.x] = s[255];
}

__global__ void k_scan3(int* __restrict__ out, const int* __restrict__ bscan, int n) {
    int i = blockIdx.x * 256 + threadIdx.x;
    if (i < n) out[i] += bscan[blockIdx.x];
}

__global__ void k_bucket(const int* __restrict__ ei, const int* __restrict__ row_start,
                         int* __restrict__ cursor, int* __restrict__ src_sorted) {
    int e = blockIdx.x * 256 + threadIdx.x;
    if (e < N_EDGES) {
        int d = ei[N_EDGES + e];
        int p = row_start[d] + atomicAdd(&cursor[d], 1);
        src_sorted[p] = ei[e];
    }
}

// ---------------- fast tanh ----------------
// tanh(x) = 1 - 2/(e^{2x}+1). Saturates correctly at +/-1; abs err ~1e-7.
__device__ __forceinline__ float fast_tanh(float x) {
    float e = __expf(2.0f * x);
    float r = __builtin_amdgcn_rcpf(e + 1.0f);
    return 1.0f - 2.0f * r;
}

// ---------------- aggregation ----------------

template <int F, bool SCALE, bool EPI>
__global__ void k_agg_small(const float* __restrict__ feat, const float* __restrict__ scale_src,
                            const int* __restrict__ row_start, const int* __restrict__ deg,
                            const int* __restrict__ src_sorted, float* __restrict__ out,
                            const float* __restrict__ inv_in, const float* __restrict__ bias) {
    int idx = blockIdx.x * 256 + threadIdx.x;
    if (idx >= N_NODES * F) return;
    int n = idx / F;
    int f = idx - n * F;
    int e = row_start[n];
    int end = e + deg[n];
    float acc = 0.f;
    for (; e < end; ++e) {
        int s = src_sorted[e];
        float v = feat[s * F + f];
        if (SCALE) v *= scale_src[s];
        acc += v;
    }
    if (EPI) acc = acc * inv_in[n] + bias[f];
    out[idx] = acc;
}

// width 220: one node per 64-lane group, lane owns 4 features (float4 gather).
// 55x b128 per edge instead of 220x b32 -> 4x fewer VMEM instructions.
__global__ __launch_bounds__(256) void k_agg220(const float* __restrict__ h,
                                                const int* __restrict__ row_start,
                                                const int* __restrict__ deg,
                                                const int* __restrict__ src_sorted,
                                                float* __restrict__ out) {
    int lane = threadIdx.x & 63;
    int n = blockIdx.x * 4 + (threadIdx.x >> 6);
    if (n >= N_NODES || lane >= 55) return;   // no barriers; early-exit safe
    int f4 = lane * 4;
    int e = row_start[n];
    int end = e + deg[n];
    float4 a0 = {0,0,0,0}, a1 = {0,0,0,0}, a2 = {0,0,0,0}, a3 = {0,0,0,0};
    for (; e + 3 < end; e += 4) {
        int sa = src_sorted[e];
        int sb = src_sorted[e + 1];
        int sc = src_sorted[e + 2];
        int sd = src_sorted[e + 3];
        float4 va = *(const float4*)&h[sa * 220 + f4];
        float4 vb = *(const float4*)&h[sb * 220 + f4];
        float4 vc = *(const float4*)&h[sc * 220 + f4];
        float4 vd = *(const float4*)&h[sd * 220 + f4];
        a0.x += va.x; a0.y += va.y; a0.z += va.z; a0.w += va.w;
        a1.x += vb.x; a1.y += vb.y; a1.z += vb.z; a1.w += vb.w;
        a2.x += vc.x; a2.y += vc.y; a2.z += vc.z; a2.w += vc.w;
        a3.x += vd.x; a3.y += vd.y; a3.z += vd.z; a3.w += vd.w;
    }
    for (; e < end; ++e) {
        float4 v = *(const float4*)&h[src_sorted[e] * 220 + f4];
        a0.x += v.x; a0.y += v.y; a0.z += v.z; a0.w += v.w;
    }
    float4 s;
    s.x = (a0.x + a1.x) + (a2.x + a3.x);
    s.y = (a0.y + a1.y) + (a2.y + a3.y);
    s.z = (a0.z + a1.z) + (a2.z + a3.z);
    s.w = (a0.w + a1.w) + (a2.w + a3.w);
    *(float4*)&out[n * 220 + f4] = s;
}

// ---------------- GEMM (fp32 vector ALU; Fout fixed = 220) ----------------
// out[n][j] = post[n] * tanh( inv_in[n]*(A[n,:] @ W)[j] + b[j] )
// 128 rows x 220 cols per 256-thread block. Per lane: 8 rows x 16 cols.
// Per kk: 2x ds_read_b128 (A) + 4x ds_read_b128 (W) = 72 LDS-pipe cyc feeding
// 128 FMA = 256 VALU cyc -> VALU-bound (round 2 was LDS-issue-bound at 14x b32
// W reads). W is quad-swizzled in LDS: word q*56+cg*4+i holds col cg*16+q*4+i,
// so each W read's 14 lane-addresses stride 4 words -> max 2-way bank aliasing
// (free). A reads: 4 addresses in distinct bank groups, 16-lane broadcast.
// LDS: A 55*132*4=29.0KB + W 55*224*4=49.3KB = 78.3KB -> 2 blocks/CU.
template <int K, int NKT>
__global__ __launch_bounds__(256, 2) void k_gemm(const float* __restrict__ A,
                                                 const float* __restrict__ Wm,
                                                 const float* __restrict__ bias,
                                                 const float* __restrict__ inv_in,
                                                 const float* __restrict__ post,
                                                 float* __restrict__ out) {
    constexpr int KT = K / NKT;        // 55 for K=220, 22 for K=22
    constexpr int AS = 132;            // 128 rows + pad (16B-aligned stride)
    constexpr int WROW = 224;          // 4 quad-blocks of 56 words
    __shared__ float s_a[KT][AS];
    __shared__ float s_w[KT][WROW];

    int tid = threadIdx.x;
    int l = tid & 63, w = tid >> 6;
    int rg4 = l & 3;                   // row-group within wave (banks spread x8)
    int cgl = l >> 2;                  // 0..15
    int cg = (cgl >= 14) ? cgl - 14 : cgl;   // effective col-group 0..13 (dups broadcast)
    bool active_c = (cgl < 14);
    int rbase = (w * 4 + rg4) * 8;     // lane's 8 contiguous local rows
    int row0 = blockIdx.x * 128;

    float acc[8][16];
#pragma unroll
    for (int r = 0; r < 8; ++r)
#pragma unroll
        for (int c = 0; c < 16; ++c) acc[r][c] = 0.f;

    for (int kt = 0; kt < NKT; ++kt) {
        int k0 = kt * KT;
        // stage A^T tile, scaled by inv_in
        for (int idx = tid; idx < 128 * KT; idx += 256) {
            int r = idx / KT;
            int kk = idx - r * KT;
            int row = row0 + r;
            float v = 0.f;
            if (row < N_NODES) v = A[row * K + k0 + kk] * inv_in[row];
            s_a[kk][r] = v;
        }
        // stage W tile, quad-swizzled, float4 global loads
        for (int idx = tid; idx < KT * 56; idx += 256) {
            int kk = idx / 56;
            int ch = idx - kk * 56;
            int q = ch / 14;
            int cgs = ch - q * 14;
            int jb = cgs * 16 + q * 4;
            float4 v = {0,0,0,0};
            if (jb <= 216) v = *(const float4*)&Wm[(k0 + kk) * 220 + jb];
            *(float4*)&s_w[kk][q * 56 + cgs * 4] = v;
        }
        __syncthreads();
#pragma unroll 2
        for (int kk = 0; kk < KT; ++kk) {
            float4 a0 = *(const float4*)&s_a[kk][rbase];
            float4 a1 = *(const float4*)&s_a[kk][rbase + 4];
            float4 w0 = *(const float4*)&s_w[kk][cg * 4];
            float4 w1 = *(const float4*)&s_w[kk][56 + cg * 4];
            float4 w2 = *(const float4*)&s_w[kk][112 + cg * 4];
            float4 w3 = *(const float4*)&s_w[kk][168 + cg * 4];
            float ar[8] = {a0.x, a0.y, a0.z, a0.w, a1.x, a1.y, a1.z, a1.w};
            float wv[16] = {w0.x, w0.y, w0.z, w0.w, w1.x, w1.y, w1.z, w1.w,
                            w2.x, w2.y, w2.z, w2.w, w3.x, w3.y, w3.z, w3.w};
#pragma unroll
            for (int r = 0; r < 8; ++r)
#pragma unroll
                for (int c = 0; c < 16; ++c) acc[r][c] += ar[r] * wv[c];
        }
        __syncthreads();
    }

    if (!active_c) return;

    // epilogue: bias + tanh + inv_sqrt_out pre-scale, float4 stores
    float bv[16];
#pragma unroll
    for (int c = 0; c < 16; ++c) {
        int j = cg * 16 + (c >> 2) * 4 + (c & 3);
        bv[c] = (j < 220) ? bias[j] : 0.f;
    }
#pragma unroll
    for (int r = 0; r < 8; ++r) {
        int row = row0 + rbase + r;
        if (row >= N_NODES) continue;
        float pv = post[row];
#pragma unroll
        for (int q = 0; q < 4; ++q) {
            int j = cg * 16 + q * 4;
            if (j <= 216) {   // only (cg==13,q==3) is fully out of range
                float4 o;
                o.x = pv * fast_tanh(acc[r][q * 4 + 0] + bv[q * 4 + 0]);
                o.y = pv * fast_tanh(acc[r][q * 4 + 1] + bv[q * 4 + 1]);
                o.z = pv * fast_tanh(acc[r][q * 4 + 2] + bv[q * 4 + 2]);
                o.w = pv * fast_tanh(acc[r][q * 4 + 3] + bv[q * 4 + 3]);
                *(float4*)&out[row * 220 + j] = o;
            }
        }
    }
}

// tmp10 = h @ W3   (h is h2 pre-scaled by inv_sqrt_out; matmul commutes with A^T)
__global__ void k_w3(const float* __restrict__ h, const float* __restrict__ W3,
                     float* __restrict__ tmp) {
    int idx = blockIdx.x * 256 + threadIdx.x;
    if (idx >= N_NODES * 10) return;
    int n = idx / 10;
    int j = idx - n * 10;
    const float2* hr = (const float2*)&h[n * 220];   // rows are 8B-aligned
    float acc = 0.f;
#pragma unroll 10
    for (int k2 = 0; k2 < 110; ++k2) {
        float2 hv = hr[k2];
        acc += hv.x * W3[(2 * k2) * 10 + j];
        acc += hv.y * W3[(2 * k2 + 1) * 10 + j];
    }
    tmp[idx] = acc;
}

// ---------------- launch ----------------

extern "C" void kernel_launch(void* const* d_in, const int* in_sizes, int n_in,
                              void* d_out, int out_size, void* d_ws, size_t ws_size,
                              hipStream_t stream) {
    const float* x  = (const float*)d_in[0];
    const float* W0 = (const float*)d_in[1];
    const float* b0 = (const float*)d_in[2];
    const float* W1 = (const float*)d_in[3];
    const float* b1 = (const float*)d_in[4];
    const float* W2 = (const float*)d_in[5];
    const float* b2 = (const float*)d_in[6];
    const float* W3 = (const float*)d_in[7];
    const float* b3 = (const float*)d_in[8];
    const int*   ei = (const int*)d_in[9];
    float* out = (float*)d_out;

    int* ws = (int*)d_ws;
    // word-offset layout (50176 = 50000 rounded up to x256)
    int* deg_out   = ws + 0;
    int* deg_in    = ws + 50176;
    int* cursor    = ws + 100352;
    int* row_start = ws + 150528;
    int* bsum      = ws + 200704;
    int* bscan     = ws + 200960;
    float* inv_out = (float*)(ws + 201216);
    float* inv_in  = (float*)(ws + 251392);
    int* src_sorted = ws + 301568;            // 800000
    float* agg  = (float*)(ws + 1101568);     // 50000*220 (also holds agg22 / tmp10)
    float* hbuf = (float*)(ws + 12101568);    // 50000*220

    // zero deg_out, deg_in, cursor (contiguous)
    hipMemsetAsync(ws, 0, (size_t)150528 * sizeof(int), stream);

    k_degrees<<<(N_EDGES + 255) / 256, 256, 0, stream>>>(ei, deg_out, deg_in);
    k_invsqrt<<<(N_NODES + 255) / 256, 256, 0, stream>>>(deg_out, deg_in, inv_out, inv_in);

    int nblk = (N_NODES + 255) / 256;   // 196
    k_scan1<<<nblk, 256, 0, stream>>>(deg_in, row_start, bsum, N_NODES);
    k_scan1<<<1, 256, 0, stream>>>(bsum, bscan, nullptr, nblk);
    k_scan3<<<nblk, 256, 0, stream>>>(row_start, bscan, N_NODES);
    k_bucket<<<(N_EDGES + 255) / 256, 256, 0, stream>>>(ei, row_start, cursor, src_sorted);

    int gemm_grid = (N_NODES + 127) / 128;   // 391
    int agg_grid = (N_NODES + 3) / 4;        // 12500

    // ---- layer 0: propagate x at width 22 (scaled by inv_out at gather), then GEMM
    k_agg_small<22, true, false><<<(N_NODES * 22 + 255) / 256, 256, 0, stream>>>(
        x, inv_out, row_start, deg_in, src_sorted, agg, nullptr, nullptr);
    k_gemm<22, 1><<<gemm_grid, 256, 0, stream>>>(agg, W0, b0, inv_in, inv_out, hbuf);

    // ---- layer 1
    k_agg220<<<agg_grid, 256, 0, stream>>>(hbuf, row_start, deg_in, src_sorted, agg);
    k_gemm<220, 4><<<gemm_grid, 256, 0, stream>>>(agg, W1, b1, inv_in, inv_out, hbuf);

    // ---- layer 2
    k_agg220<<<agg_grid, 256, 0, stream>>>(hbuf, row_start, deg_in, src_sorted, agg);
    k_gemm<220, 4><<<gemm_grid, 256, 0, stream>>>(agg, W2, b2, inv_in, inv_out, hbuf);

    // ---- layer 3: GEMM first (width 10), then propagate + epilogue straight to d_out
    k_w3<<<(N_NODES * 10 + 255) / 256, 256, 0, stream>>>(hbuf, W3, agg);
    k_agg_small<10, false, true><<<(N_NODES * 10 + 255) / 256, 256, 0, stream>>>(
        agg, nullptr, row_start, deg_in, src_sorted, out, inv_in, b3);
}

// Round 4
// 718.898 us; speedup vs baseline: 1.3214x; 1.3214x over previous
//
#include <hip/hip_runtime.h>
#include <math.h>

#define N_NODES 50000
#define N_EDGES 800000

typedef __attribute__((ext_vector_type(8))) short short8;
typedef __attribute__((ext_vector_type(4))) float f32x4;

// ---------------- degree / CSR build ----------------

__global__ void k_degrees(const int* __restrict__ ei, int* __restrict__ deg_out,
                          int* __restrict__ deg_in) {
    int e = blockIdx.x * 256 + threadIdx.x;
    if (e < N_EDGES) {
        atomicAdd(&deg_out[ei[e]], 1);
        atomicAdd(&deg_in[ei[N_EDGES + e]], 1);
    }
}

__global__ void k_invsqrt(const int* __restrict__ deg_out, const int* __restrict__ deg_in,
                          float* __restrict__ inv_out, float* __restrict__ inv_in) {
    int n = blockIdx.x * 256 + threadIdx.x;
    if (n < N_NODES) {
        int a = deg_out[n]; if (a < 1) a = 1;
        int b = deg_in[n];  if (b < 1) b = 1;
        inv_out[n] = 1.0f / sqrtf((float)a);
        inv_in[n]  = 1.0f / sqrtf((float)b);
    }
}

__global__ void k_scan1(const int* __restrict__ in, int* __restrict__ out,
                        int* __restrict__ bsum, int n) {
    __shared__ int s[256];
    int i = blockIdx.x * 256 + threadIdx.x;
    int v = (i < n) ? in[i] : 0;
    s[threadIdx.x] = v;
    __syncthreads();
    for (int off = 1; off < 256; off <<= 1) {
        int t = (threadIdx.x >= off) ? s[threadIdx.x - off] : 0;
        __syncthreads();
        s[threadIdx.x] += t;
        __syncthreads();
    }
    if (i < n) out[i] = s[threadIdx.x] - v;   // exclusive
    if (threadIdx.x == 255 && bsum) bsum[blockIdx.x] = s[255];
}

__global__ void k_scan3(int* __restrict__ out, const int* __restrict__ bscan, int n) {
    int i = blockIdx.x * 256 + threadIdx.x;
    if (i < n) out[i] += bscan[blockIdx.x];
}

__global__ void k_bucket(const int* __restrict__ ei, const int* __restrict__ row_start,
                         int* __restrict__ cursor, int* __restrict__ src_sorted) {
    int e = blockIdx.x * 256 + threadIdx.x;
    if (e < N_EDGES) {
        int d = ei[N_EDGES + e];
        int p = row_start[d] + atomicAdd(&cursor[d], 1);
        src_sorted[p] = ei[e];
    }
}

// ---------------- helpers ----------------

__device__ __forceinline__ float fast_tanh(float x) {
    float e = __expf(2.0f * x);
    float r = __builtin_amdgcn_rcpf(e + 1.0f);
    return 1.0f - 2.0f * r;
}

// round-to-nearest-even fp32 -> bf16
__device__ __forceinline__ unsigned short rne_bf16(float x) {
    unsigned u = __builtin_bit_cast(unsigned, x);
    return (unsigned short)((u + 0x7FFFu + ((u >> 16) & 1u)) >> 16);
}

// split x = hi + lo (both bf16), |err| ~ 2^-17 |x|
__device__ __forceinline__ void split_bf16(float x, unsigned short& hi, unsigned short& lo) {
    hi = rne_bf16(x);
    float hf = __builtin_bit_cast(float, (unsigned)hi << 16);
    lo = rne_bf16(x - hf);
}

__device__ __forceinline__ f32x4 mfma16(short8 a, short8 b, f32x4 c) {
    return __builtin_amdgcn_mfma_f32_16x16x32_bf16(a, b, c, 0, 0, 0);
}

// ---------------- aggregation ----------------

template <int F, bool SCALE, bool EPI>
__global__ void k_agg_small(const float* __restrict__ feat, const float* __restrict__ scale_src,
                            const int* __restrict__ row_start, const int* __restrict__ deg,
                            const int* __restrict__ src_sorted, float* __restrict__ out,
                            const float* __restrict__ inv_in, const float* __restrict__ bias) {
    int idx = blockIdx.x * 256 + threadIdx.x;
    if (idx >= N_NODES * F) return;
    int n = idx / F;
    int f = idx - n * F;
    int e = row_start[n];
    int end = e + deg[n];
    float acc = 0.f;
    for (; e < end; ++e) {
        int s = src_sorted[e];
        float v = feat[s * F + f];
        if (SCALE) v *= scale_src[s];
        acc += v;
    }
    if (EPI) acc = acc * inv_in[n] + bias[f];
    out[idx] = acc;
}

// width-220 gather + fused (sum*inv_in) -> bf16 hi/lo split, written to the
// MFMA A buffers (row stride 224, cols 220..223 zeroed by lane 55).
// One node per 64-lane group; lanes 0..54 own 4 features each (float4 gather).
__global__ __launch_bounds__(256) void k_agg220_split(const float* __restrict__ h,
                                                      const int* __restrict__ row_start,
                                                      const int* __restrict__ deg,
                                                      const int* __restrict__ src_sorted,
                                                      const float* __restrict__ inv_in,
                                                      unsigned short* __restrict__ A_hi,
                                                      unsigned short* __restrict__ A_lo) {
    int lane = threadIdx.x & 63;
    int n = blockIdx.x * 4 + (threadIdx.x >> 6);
    if (n >= N_NODES || lane >= 56) return;   // no barriers; early-exit safe
    size_t obase = (size_t)n * 224 + lane * 4;
    if (lane == 55) {                          // K-pad columns 220..223 = 0
        ushort4 z = {0, 0, 0, 0};
        *(ushort4*)&A_hi[obase] = z;
        *(ushort4*)&A_lo[obase] = z;
        return;
    }
    int f4 = lane * 4;
    int e = row_start[n];
    int end = e + deg[n];
    float4 a0 = {0,0,0,0}, a1 = {0,0,0,0}, a2 = {0,0,0,0}, a3 = {0,0,0,0};
    for (; e + 3 < end; e += 4) {
        int sa = src_sorted[e];
        int sb = src_sorted[e + 1];
        int sc = src_sorted[e + 2];
        int sd = src_sorted[e + 3];
        float4 va = *(const float4*)&h[sa * 220 + f4];
        float4 vb = *(const float4*)&h[sb * 220 + f4];
        float4 vc = *(const float4*)&h[sc * 220 + f4];
        float4 vd = *(const float4*)&h[sd * 220 + f4];
        a0.x += va.x; a0.y += va.y; a0.z += va.z; a0.w += va.w;
        a1.x += vb.x; a1.y += vb.y; a1.z += vb.z; a1.w += vb.w;
        a2.x += vc.x; a2.y += vc.y; a2.z += vc.z; a2.w += vc.w;
        a3.x += vd.x; a3.y += vd.y; a3.z += vd.z; a3.w += vd.w;
    }
    for (; e < end; ++e) {
        float4 v = *(const float4*)&h[src_sorted[e] * 220 + f4];
        a0.x += v.x; a0.y += v.y; a0.z += v.z; a0.w += v.w;
    }
    float s = inv_in[n];
    float v0 = ((a0.x + a1.x) + (a2.x + a3.x)) * s;
    float v1 = ((a0.y + a1.y) + (a2.y + a3.y)) * s;
    float v2 = ((a0.z + a1.z) + (a2.z + a3.z)) * s;
    float v3 = ((a0.w + a1.w) + (a2.w + a3.w)) * s;
    ushort4 hi, lo;
    split_bf16(v0, hi.x, lo.x);
    split_bf16(v1, hi.y, lo.y);
    split_bf16(v2, hi.z, lo.z);
    split_bf16(v3, hi.w, lo.w);
    *(ushort4*)&A_hi[obase] = hi;
    *(ushort4*)&A_lo[obase] = lo;
}

// W [220x220 fp32, k-major] -> WT_hi/WT_lo [224x224 bf16, n-major: WT[n][k]]
__global__ void k_wsplit(const float* __restrict__ W, unsigned short* __restrict__ WT_hi,
                         unsigned short* __restrict__ WT_lo) {
    int idx = blockIdx.x * 256 + threadIdx.x;   // n*224 + k
    if (idx >= 224 * 224) return;
    int n = idx / 224;
    int k = idx - n * 224;
    float v = (n < 220 && k < 220) ? W[k * 220 + n] : 0.f;
    unsigned short hi, lo;
    split_bf16(v, hi, lo);
    WT_hi[idx] = hi;
    WT_lo[idx] = lo;
}

// ---------------- MFMA split-bf16 GEMM (K=224, N=220) ----------------
// D = A@W to ~fp32 precision via A_hi*W_hi + A_hi*W_lo + A_lo*W_hi.
// out[n][j] = post[n] * tanh(D[n][j] + bias[j]);  inv_in pre-folded into A.
// Wave = 16 rows x 224 cols (14 col-tiles of 16x16x32 mfma, acc 56 VGPRs).
// No LDS, no barriers: A frags (row-major, stride 224) and B frags
// (WT n-major, stride 224) are direct dwordx4 loads, L1/L2-resident.
__global__ __launch_bounds__(256) void k_gemm_mfma(const unsigned short* __restrict__ A_hi,
                                                   const unsigned short* __restrict__ A_lo,
                                                   const unsigned short* __restrict__ WT_hi,
                                                   const unsigned short* __restrict__ WT_lo,
                                                   const float* __restrict__ bias,
                                                   const float* __restrict__ post,
                                                   float* __restrict__ out) {
    int tid = threadIdx.x;
    int l = tid & 63, w = tid >> 6;
    int lrow = l & 15, q = l >> 4;
    int rtile = blockIdx.x * 64 + w * 16;

    // A operand: lane holds A[m = rtile + lrow][k = ks*32 + q*8 + j], j=0..7
    const unsigned short* pah = A_hi + (size_t)(rtile + lrow) * 224 + q * 8;
    const unsigned short* pal = A_lo + (size_t)(rtile + lrow) * 224 + q * 8;

    f32x4 acc[14];
#pragma unroll
    for (int ct = 0; ct < 14; ++ct) acc[ct] = (f32x4){0.f, 0.f, 0.f, 0.f};

#pragma unroll
    for (int ks = 0; ks < 7; ++ks) {
        int k0 = ks * 32;
        short8 ah = *(const short8*)(const void*)(pah + k0);
        short8 al = *(const short8*)(const void*)(pal + k0);
#pragma unroll
        for (int ct = 0; ct < 14; ++ct) {
            // B operand: lane holds W[k = ks*32 + q*8 + j][n = ct*16 + lrow]
            size_t boff = (size_t)(ct * 16 + lrow) * 224 + q * 8 + k0;
            short8 bh = *(const short8*)(const void*)(WT_hi + boff);
            short8 bl = *(const short8*)(const void*)(WT_lo + boff);
            acc[ct] = mfma16(ah, bh, acc[ct]);
            acc[ct] = mfma16(ah, bl, acc[ct]);
            acc[ct] = mfma16(al, bh, acc[ct]);
        }
    }

    // epilogue: C/D layout col = ct*16 + (l&15), row = rtile + q*4 + r
    float pv[4];
#pragma unroll
    for (int r = 0; r < 4; ++r) {
        int row = rtile + q * 4 + r;
        pv[r] = (row < N_NODES) ? post[row] : 0.f;
    }
#pragma unroll
    for (int ct = 0; ct < 14; ++ct) {
        int col = ct * 16 + lrow;
        if (col >= 220) continue;   // ct==13, lanes 12..15
        float bv = bias[col];
#pragma unroll
        for (int r = 0; r < 4; ++r) {
            int row = rtile + q * 4 + r;
            if (row < N_NODES)
                out[(size_t)row * 220 + col] = pv[r] * fast_tanh(acc[ct][r] + bv);
        }
    }
}

// ---------------- fp32 vector GEMM (layer 0 only, K=22) ----------------
// Round-2 proven version: 128 rows x 220 cols, acc[8][14], 124 VGPR.
template <int K, int NKT>
__global__ __launch_bounds__(256, 2) void k_gemm(const float* __restrict__ A,
                                                 const float* __restrict__ Wm,
                                                 const float* __restrict__ bias,
                                                 const float* __restrict__ inv_in,
                                                 const float* __restrict__ post,
                                                 float* __restrict__ out) {
    constexpr int KT = K / NKT;
    constexpr int AS = 132;
    constexpr int WS = 224;
    __shared__ float s_a[KT][AS];
    __shared__ float s_w[KT][WS];

    int tid = threadIdx.x;
    int l = tid & 63, w = tid >> 6;
    int rg = l >> 4;
    int cg = l & 15;
    int rbase = w * 32 + rg * 8;
    int row0 = blockIdx.x * 128;

    float acc[8][14];
#pragma unroll
    for (int r = 0; r < 8; ++r)
#pragma unroll
        for (int c = 0; c < 14; ++c) acc[r][c] = 0.f;

    for (int kt = 0; kt < NKT; ++kt) {
        int k0 = kt * KT;
        for (int idx = tid; idx < 128 * KT; idx += 256) {
            int r = idx / KT;
            int kk = idx - r * KT;
            int row = row0 + r;
            float v = 0.f;
            if (row < N_NODES) v = A[row * K + k0 + kk] * inv_in[row];
            s_a[kk][r] = v;
        }
        for (int idx = tid; idx < KT * 220; idx += 256) {
            int kk = idx / 220;
            int j = idx - kk * 220;
            s_w[kk][j] = Wm[(k0 + kk) * 220 + j];
        }
        __syncthreads();
#pragma unroll 2
        for (int kk = 0; kk < KT; ++kk) {
            float4 a0 = *(const float4*)&s_a[kk][rbase];
            float4 a1 = *(const float4*)&s_a[kk][rbase + 4];
#pragma unroll
            for (int c = 0; c < 14; ++c) {
                float wv = s_w[kk][cg + 16 * c];
                acc[0][c] += a0.x * wv;
                acc[1][c] += a0.y * wv;
                acc[2][c] += a0.z * wv;
                acc[3][c] += a0.w * wv;
                acc[4][c] += a1.x * wv;
                acc[5][c] += a1.y * wv;
                acc[6][c] += a1.z * wv;
                acc[7][c] += a1.w * wv;
            }
        }
        __syncthreads();
    }

    float bv[14];
#pragma unroll
    for (int c = 0; c < 14; ++c) {
        int j = cg + 16 * c;
        bv[c] = (j < 220) ? bias[j] : 0.f;
    }
#pragma unroll
    for (int r = 0; r < 8; ++r) {
        int row = row0 + rbase + r;
        if (row >= N_NODES) continue;
        float pvv = post[row];
#pragma unroll
        for (int c = 0; c < 14; ++c) {
            int j = cg + 16 * c;
            if (j < 220) out[row * 220 + j] = pvv * fast_tanh(acc[r][c] + bv[c]);
        }
    }
}

// tmp10 = h @ W3
__global__ void k_w3(const float* __restrict__ h, const float* __restrict__ W3,
                     float* __restrict__ tmp) {
    int idx = blockIdx.x * 256 + threadIdx.x;
    if (idx >= N_NODES * 10) return;
    int n = idx / 10;
    int j = idx - n * 10;
    const float2* hr = (const float2*)&h[n * 220];
    float acc = 0.f;
#pragma unroll 10
    for (int k2 = 0; k2 < 110; ++k2) {
        float2 hv = hr[k2];
        acc += hv.x * W3[(2 * k2) * 10 + j];
        acc += hv.y * W3[(2 * k2 + 1) * 10 + j];
    }
    tmp[idx] = acc;
}

// ---------------- launch ----------------

extern "C" void kernel_launch(void* const* d_in, const int* in_sizes, int n_in,
                              void* d_out, int out_size, void* d_ws, size_t ws_size,
                              hipStream_t stream) {
    const float* x  = (const float*)d_in[0];
    const float* W0 = (const float*)d_in[1];
    const float* b0 = (const float*)d_in[2];
    const float* W1 = (const float*)d_in[3];
    const float* b1 = (const float*)d_in[4];
    const float* W2 = (const float*)d_in[5];
    const float* b2 = (const float*)d_in[6];
    const float* W3 = (const float*)d_in[7];
    const float* b3 = (const float*)d_in[8];
    const int*   ei = (const int*)d_in[9];
    float* out = (float*)d_out;

    int* ws = (int*)d_ws;
    // word offsets
    int* deg_out   = ws + 0;
    int* deg_in    = ws + 50176;
    int* cursor    = ws + 100352;
    int* row_start = ws + 150528;
    int* bsum      = ws + 200704;
    int* bscan     = ws + 200960;
    float* inv_out = (float*)(ws + 201216);
    float* inv_in  = (float*)(ws + 251392);
    int* src_sorted = ws + 301568;                         // 800000
    float* f32s = (float*)(ws + 1101568);                  // 1.1M: agg22 / tmp10
    unsigned short* wt1h = (unsigned short*)(ws + 2201568); // 25088 words each
    unsigned short* wt1l = (unsigned short*)(ws + 2226656);
    unsigned short* wt2h = (unsigned short*)(ws + 2251744);
    unsigned short* wt2l = (unsigned short*)(ws + 2276832);
    unsigned short* ahi = (unsigned short*)(ws + 2301920); // 50176x224 bf16 = 5619712 words
    unsigned short* alo = (unsigned short*)(ws + 7921632); // 5619712 words
    float* hbuf = (float*)(ws + 13541344);                 // 50000*220

    hipMemsetAsync(ws, 0, (size_t)150528 * sizeof(int), stream);

    k_degrees<<<(N_EDGES + 255) / 256, 256, 0, stream>>>(ei, deg_out, deg_in);
    k_invsqrt<<<(N_NODES + 255) / 256, 256, 0, stream>>>(deg_out, deg_in, inv_out, inv_in);

    int nblk = (N_NODES + 255) / 256;
    k_scan1<<<nblk, 256, 0, stream>>>(deg_in, row_start, bsum, N_NODES);
    k_scan1<<<1, 256, 0, stream>>>(bsum, bscan, nullptr, nblk);
    k_scan3<<<nblk, 256, 0, stream>>>(row_start, bscan, N_NODES);
    k_bucket<<<(N_EDGES + 255) / 256, 256, 0, stream>>>(ei, row_start, cursor, src_sorted);

    // W1/W2 -> transposed bf16 hi/lo splits (independent; run early)
    k_wsplit<<<196, 256, 0, stream>>>(W1, wt1h, wt1l);
    k_wsplit<<<196, 256, 0, stream>>>(W2, wt2h, wt2l);

    int agg_grid  = (N_NODES + 3) / 4;        // 12500
    int mfma_grid = (N_NODES + 63) / 64;      // 782

    // ---- layer 0: propagate x at width 22, fp32 GEMM (K=22)
    k_agg_small<22, true, false><<<(N_NODES * 22 + 255) / 256, 256, 0, stream>>>(
        x, inv_out, row_start, deg_in, src_sorted, f32s, nullptr, nullptr);
    k_gemm<22, 1><<<(N_NODES + 127) / 128, 256, 0, stream>>>(f32s, W0, b0, inv_in, inv_out, hbuf);

    // ---- layer 1: gather+split, MFMA GEMM
    k_agg220_split<<<agg_grid, 256, 0, stream>>>(hbuf, row_start, deg_in, src_sorted,
                                                 inv_in, ahi, alo);
    k_gemm_mfma<<<mfma_grid, 256, 0, stream>>>(ahi, alo, wt1h, wt1l, b1, inv_out, hbuf);

    // ---- layer 2
    k_agg220_split<<<agg_grid, 256, 0, stream>>>(hbuf, row_start, deg_in, src_sorted,
                                                 inv_in, ahi, alo);
    k_gemm_mfma<<<mfma_grid, 256, 0, stream>>>(ahi, alo, wt2h, wt2l, b2, inv_out, hbuf);

    // ---- layer 3: GEMM first (width 10), then propagate + epilogue to d_out
    k_w3<<<(N_NODES * 10 + 255) / 256, 256, 0, stream>>>(hbuf, W3, f32s);
    k_agg_small<10, false, true><<<(N_NODES * 10 + 255) / 256, 256, 0, stream>>>(
        f32s, nullptr, row_start, deg_in, src_sorted, out, inv_in, b3);
}